// Round 1
// 339.564 us; speedup vs baseline: 1.0901x; 1.0901x over previous
//
#include <hip/hip_runtime.h>
#include <hip/hip_bf16.h>

#define NN 50000
#define EE 100000
#define FF 64
#define HH 128
#define HEADS 4
#define BB 64
#define SS 512
#define LCC 8

// ---- bf16 helpers ----
__device__ __forceinline__ float b2f(ushort u) {
    return __uint_as_float(((unsigned)u) << 16);
}
__device__ __forceinline__ ushort f2b(float f) {
    unsigned u = __float_as_uint(f);
    unsigned r = (u + 0x7FFFu + ((u >> 16) & 1u)) >> 16;   // RNE
    return (ushort)r;
}
// packed RNE convert: 2 f32 -> 1 uint (low = a), maps to v_cvt_pk_bf16_f32
__device__ __forceinline__ uint f2b_pk(float a, float b) {
    __hip_bfloat162 h = __float22bfloat162_rn(make_float2(a, b));
    return *reinterpret_cast<uint*>(&h);
}

// ---- fp8 (OCP e4m3fn) helpers: HW cvt on gfx950 ----
// values are stored pre-scaled x16 to stay in the normal range (sigma ~0.006-0.04)
__device__ __forceinline__ uint f2fp8x4(float a, float b, float c, float d) {
    int r = __builtin_amdgcn_cvt_pk_fp8_f32(a, b, 0, false);   // bytes 0,1
    r = __builtin_amdgcn_cvt_pk_fp8_f32(c, d, r, true);        // bytes 2,3
    return (uint)r;
}
__device__ __forceinline__ float fp8lo(ushort u) { return __builtin_amdgcn_cvt_f32_fp8((int)u, 0); }
__device__ __forceinline__ float fp8hi(ushort u) { return __builtin_amdgcn_cvt_f32_fp8((int)u, 1); }

typedef __attribute__((ext_vector_type(4))) float f32x4;
typedef __attribute__((ext_vector_type(8))) short s16x8;
typedef __attribute__((ext_vector_type(4))) uint u32x4;

__device__ __forceinline__ void glls16(const ushort* g, ushort* l) {
    __builtin_amdgcn_global_load_lds((const __attribute__((address_space(1))) void*)g,
                                     (__attribute__((address_space(3))) void*)l, 16, 0, 0);
}

// ================= bf16 MFMA GEMM (r12-proven core; bf16 or fp8 epilogue) =================
#define BM 128
#define BN 128
#define BK 64
#define EST 68   // epilogue staging stride (f32) — breaks power-of-2 bank aliasing

__global__ __launch_bounds__(256) void gemm_bf16(
    const ushort* __restrict__ A, const ushort* __restrict__ Bt,
    const float* __restrict__ bias,
    ushort* __restrict__ C1, int ld1,
    ushort* __restrict__ C2b, int mode,
    int M, int K, int relu, int gx, int gy)
{
    __shared__ __align__(16) ushort Sm[2 * BM * BK];   // 32 KB: As | Bs, reused by epilogue
    ushort* As = Sm;
    ushort* Bs = Sm + BM * BK;

    const int bid  = blockIdx.x;
    const int xcd  = bid & 7;
    const int slot = bid >> 3;
    const int bx   = slot % gx;
    const int by   = xcd + 8 * (slot / gx);
    if (by >= gy) return;
    const int m0 = by * BM;
    const int n0 = bx * BN;

    const int t = threadIdx.x;
    const int lane = t & 63;
    const int wave = t >> 6;
    const int wm = (wave & 1) * 64;
    const int wn = (wave >> 1) * 64;
    const int lrow = lane & 15;
    const int g    = lane >> 4;

    const int wbase = n0 + wn;
    float bj[4];
#pragma unroll
    for (int j = 0; j < 4; ++j) bj[j] = bias[wbase + j * 16 + lrow];

    const int srow = (wave << 5) + (lane >> 3);
    const int scs  = lane & 7;

    const ushort* ga[4];
    const ushort* gb[4];
#pragma unroll
    for (int p = 0; p < 4; ++p) {
        const int row = srow + (p << 3);
        const int l   = scs ^ (row & 7);
        ga[p] = A + (size_t)min(m0 + row, M - 1) * K + (l << 3);
        gb[p] = Bt + (size_t)(n0 + row) * K + (l << 3);
    }
    const int ldsoff = (wave << 11);

    // bias folded into acc init (kills 64 epilogue fadds/lane)
    f32x4 acc[4][4];
#pragma unroll
    for (int i = 0; i < 4; ++i)
#pragma unroll
        for (int j = 0; j < 4; ++j)
            acc[i][j] = (f32x4){bj[j], bj[j], bj[j], bj[j]};

    for (int k0 = 0; k0 < K; k0 += BK) {
#pragma unroll
        for (int p = 0; p < 4; ++p) glls16(ga[p] + k0, As + ldsoff + (p << 9));
#pragma unroll
        for (int p = 0; p < 4; ++p) glls16(gb[p] + k0, Bs + ldsoff + (p << 9));
        __syncthreads();

#pragma unroll
        for (int kk = 0; kk < 2; ++kk) {
            s16x8 af[4], bf[4];
#pragma unroll
            for (int i = 0; i < 4; ++i) {
                const int R = wm + i * 16 + lrow;
                const int c = ((kk << 2) + g) ^ (R & 7);
                af[i] = *(const s16x8*)&As[(R << 6) + (c << 3)];
            }
#pragma unroll
            for (int j = 0; j < 4; ++j) {
                const int R = wn + j * 16 + lrow;
                const int c = ((kk << 2) + g) ^ (R & 7);
                bf[j] = *(const s16x8*)&Bs[(R << 6) + (c << 3)];
            }
#pragma unroll
            for (int i = 0; i < 4; ++i)
#pragma unroll
                for (int j = 0; j < 4; ++j)
                    acc[i][j] = __builtin_amdgcn_mfma_f32_16x16x32_bf16(af[i], bf[j], acc[i][j], 0, 0, 0);
        }
        __syncthreads();
    }

    // ---- LDS-staged epilogue (bf16 or fp8 stream per wave) ----
    float* Es = (float*)Sm + wave * (16 * EST);

    bool e8 = false;
    ushort* Cw = C1; int ldw = ld1; int cb = wbase;
    unsigned char* Cw8 = nullptr;
    if (mode == 1) {
        if (wbase >= 512) {                   // per-head u|v buffer, fp8 rows of 256 B
            e8 = true;
            const int u = wbase - 512;
            const int h = u >> 8;
            cb = u & 255;
            Cw8 = (unsigned char*)C2b + (size_t)h * NN * 256;
            ldw = 256;
        }
    } else if (mode == 2) {
        if (wbase < 128) { ldw = 128; }
        else {                                // q|k|v buffer, fp8 rows of 384 B
            e8 = true;
            Cw8 = (unsigned char*)C2b;
            ldw = 384;
            cb = wbase - 128;
        }
    }

    const int rbase = (lane >> 4) * 4;
    const int rrow  = lane >> 2;
    const int rcol  = (lane & 3) << 4;

#pragma unroll
    for (int i = 0; i < 4; ++i) {
#pragma unroll
        for (int j = 0; j < 4; ++j)
#pragma unroll
            for (int r = 0; r < 4; ++r) {
                float v = acc[i][j][r];
                if (relu) v = fmaxf(v, 0.f);
                Es[(rbase + r) * EST + j * 16 + lrow] = v;
            }
        const int gm = m0 + wm + i * 16 + rrow;
        if (gm < M) {
            const float* srcp = Es + rrow * EST + rcol;
            f32x4 f0 = *(const f32x4*)(srcp + 0);
            f32x4 f1 = *(const f32x4*)(srcp + 4);
            f32x4 f2 = *(const f32x4*)(srcp + 8);
            f32x4 f3 = *(const f32x4*)(srcp + 12);
            if (!e8) {
                u32x4 o0, o1;
                o0[0] = f2b_pk(f0[0], f0[1]); o0[1] = f2b_pk(f0[2], f0[3]);
                o0[2] = f2b_pk(f1[0], f1[1]); o0[3] = f2b_pk(f1[2], f1[3]);
                o1[0] = f2b_pk(f2[0], f2[1]); o1[1] = f2b_pk(f2[2], f2[3]);
                o1[2] = f2b_pk(f3[0], f3[1]); o1[3] = f2b_pk(f3[2], f3[3]);
                ushort* dst = Cw + (size_t)gm * ldw + cb + rcol;
                *(u32x4*)(dst + 0) = o0;
                *(u32x4*)(dst + 8) = o1;
            } else {
                u32x4 o;
                o[0] = f2fp8x4(f0[0], f0[1], f0[2], f0[3]);
                o[1] = f2fp8x4(f1[0], f1[1], f1[2], f1[3]);
                o[2] = f2fp8x4(f2[0], f2[1], f2[2], f2[3]);
                o[3] = f2fp8x4(f3[0], f3[1], f3[2], f3[3]);
                *(u32x4*)(Cw8 + (size_t)gm * ldw + cb + rcol) = o;
            }
        }
    }
}

// ================= weight prep + mcomp fused (disjoint writes) =================
// wt layout (rows [n][k], bf16):
//  [0, 8192)            Wpt   [128][64]
//  [8192, 204800)       F1    [1536][128] = Ws1t(512) | per head: u(128, 16*M) | v(128, 16*Wv1)
//  [204800, 466944)     F2    [512][512]  = Ws2t(128) | 16*(q2|k2|v2) (384)
// bb: [0,512) bs1; per head [512+h*256,+128) 16*r_h, [+128,+256) 16*bv1; [1536,2048) F2
//     (F2: bs2 | 16*bq2 | 16*bk2 | 16*bv2)
// fp8 streams are stored x16 pre-scaled; gathers divide back out.
#define F1OFF  8192
#define F2OFF  204800
#define WTOTAL 466944
#define BTOT   2048
#define MWORK  (HEADS * 128 * 128 + HEADS * 128)   // 66048

__global__ void prep_kernel(
    const float* __restrict__ Wp,
    const float* __restrict__ Wq1, const float* __restrict__ Wk1,
    const float* __restrict__ Wv1, const float* __restrict__ Ws1,
    const float* __restrict__ Wq2, const float* __restrict__ Wk2,
    const float* __restrict__ Wv2, const float* __restrict__ Ws2,
    const float* __restrict__ bs1, const float* __restrict__ bq1,
    const float* __restrict__ bv1, const float* __restrict__ bs2,
    const float* __restrict__ bq2, const float* __restrict__ bk2, const float* __restrict__ bv2,
    ushort* __restrict__ wt, float* __restrict__ bb)
{
    int t = blockIdx.x * 256 + threadIdx.x;
    if (t < WTOTAL) {
        float v;
        if (t < F1OFF) {
            int n = t >> 6, k = t & 63;
            v = Wp[k * 128 + n];
        } else if (t < F2OFF) {
            int u = t - F1OFF;
            int n = u >> 7, k = u & 127;
            if (n < 512) v = Ws1[k * 512 + n];
            else {
                int r = n - 512;
                int h = r >> 8, c = r & 255;
                if (c < 128) return;             // u (M) rows: filled by mcomp branch
                v = Wv1[k * 512 + h * 128 + (c - 128)] * 16.0f;
            }
        } else {
            int u = t - F2OFF;
            int n = u >> 9, k = u & 511;
            if (n < 128) v = Ws2[k * 128 + n];
            else {
                int r = n - 128;
                const float* W = (r < 128) ? Wq2 : (r < 256) ? Wk2 : Wv2;
                v = W[k * 128 + (r & 127)] * 16.0f;
            }
        }
        wt[t] = f2b(v);
    } else if (t < WTOTAL + BTOT) {
        int u = t - WTOTAL;
        float v;
        if (u < 512) v = bs1[u];
        else if (u < 1536) {
            int r = u - 512;
            int h = r >> 8, c = r & 255;
            if (c < 128) return;                 // r_h bias: filled by mcomp branch
            v = bv1[h * 128 + (c - 128)] * 16.0f;
        } else {
            int c = u - 1536;
            v = (c < 128) ? bs2[c]
              : (c < 256) ? bq2[c - 128] * 16.0f
              : (c < 384) ? bk2[c - 256] * 16.0f : bv2[c - 384] * 16.0f;
        }
        bb[u] = v;
    } else if (t < WTOTAL + BTOT + MWORK) {
        int m = t - (WTOTAL + BTOT);
        if (m < HEADS * 128 * 128) {             // M_h[a][b] = Wq_h[:,a] . Wk_h[:,b]
            int h = m >> 14;
            int rem = m & 16383;
            int b = rem >> 7, a = rem & 127;
            const float* wq = Wq1 + a * 512 + h * 128;
            const float* wk = Wk1 + b * 512 + h * 128;
            float acc = 0.f;
#pragma unroll 8
            for (int d = 0; d < 128; ++d) acc += wq[d] * wk[d];
            wt[F1OFF + (size_t)(512 + h * 256 + b) * 128 + a] = f2b(acc * 16.0f);
        } else {                                 // r_h[b] = Wk_h[:,b] . bq_h
            int u = m - HEADS * 128 * 128;
            int h = u >> 7, b = u & 127;
            const float* wk = Wk1 + b * 512 + h * 128;
            const float* bq = bq1 + h * 128;
            float acc = 0.f;
#pragma unroll 8
            for (int d = 0; d < 128; ++d) acc += wk[d] * bq[d];
            bb[512 + h * 256 + b] = acc * 16.0f;
        }
    }
}

// ================= fp32 -> bf16 (x4, packed cvt) =================
__global__ void f32_to_bf16_kernel(const float4* __restrict__ in, uint2* __restrict__ out, int n4)
{
    int i = blockIdx.x * 256 + threadIdx.x;
    if (i >= n4) return;
    float4 v = in[i];
    uint2 o;
    o.x = f2b_pk(v.x, v.y);
    o.y = f2b_pk(v.z, v.w);
    out[i] = o;
}

__global__ void fill_kernel(unsigned* __restrict__ p, unsigned v, int n) {
    int i = blockIdx.x * blockDim.x + threadIdx.x;
    if (i < n) p[i] = v;
}

// ================= CSR build (dst -> src list) =================
__global__ void hist_kernel(const int* __restrict__ dst, int* __restrict__ cnt, int E) {
    int e = blockIdx.x * 256 + threadIdx.x;
    if (e < E) atomicAdd(&cnt[dst[e]], 1);
}

#define SCAN_B 1024
__global__ void scan_bsum_kernel(const int* __restrict__ cnt, int* __restrict__ bsum, int n) {
    __shared__ int sd[256];
    int tid = threadIdx.x;
    int base = blockIdx.x * SCAN_B + tid * 4;
    int s = 0;
#pragma unroll
    for (int j = 0; j < 4; ++j) if (base + j < n) s += cnt[base + j];
    sd[tid] = s;
    __syncthreads();
    for (int off = 128; off > 0; off >>= 1) {
        if (tid < off) sd[tid] += sd[tid + off];
        __syncthreads();
    }
    if (tid == 0) bsum[blockIdx.x] = sd[0];
}

// scan_final with fused exclusive block-prefix (reads RAW bsum; no scan_excl pass)
__global__ void scan_final_kernel(const int* __restrict__ cnt, const int* __restrict__ bsum,
                                  int* __restrict__ rowptr, int* __restrict__ cursor, int n) {
    __shared__ int sd[256];
    __shared__ int sb[256];
    int tid = threadIdx.x;
    sb[tid] = (tid < blockIdx.x) ? bsum[tid] : 0;
    __syncthreads();
    for (int off = 128; off > 0; off >>= 1) {
        if (tid < off) sb[tid] += sb[tid + off];
        __syncthreads();
    }
    const int bbase = sb[0];

    int base = blockIdx.x * SCAN_B + tid * 4;
    int v[4]; int s = 0;
#pragma unroll
    for (int j = 0; j < 4; ++j) { v[j] = (base + j < n) ? cnt[base + j] : 0; s += v[j]; }
    sd[tid] = s;
    __syncthreads();
    for (int off = 1; off < 256; off <<= 1) {
        int t2 = (tid >= off) ? sd[tid - off] : 0;
        __syncthreads();
        sd[tid] += t2;
        __syncthreads();
    }
    int acc = bbase + sd[tid] - s;
#pragma unroll
    for (int j = 0; j < 4; ++j) {
        if (base + j < n) cursor[base + j] = acc;
        acc += v[j];
        if (base + j < n) rowptr[base + j + 1] = acc;
    }
    if (blockIdx.x == 0 && tid == 0) rowptr[0] = 0;
}

__global__ void bucket_kernel(const int* __restrict__ src, const int* __restrict__ dst,
                              int* __restrict__ cursor, int* __restrict__ srcs, int E) {
    int e = blockIdx.x * 256 + threadIdx.x;
    if (e >= E) return;
    int p = atomicAdd(&cursor[dst[e]], 1);
    srcs[p] = src[e];
}

// ================= conv1 gather: ALL 4 HEADS per wave, ILP-2 over edges =================
// Qb: 4 fp8 head buffers (stride NN*256 B), row = [u(128)|v(128)] fp8, x16 pre-scaled.
// Kb = h0 rows (128 bf16). io: h1b rows (512 bf16) — skip in, result out, in place.
// scale arg is pre-divided by 16 (u pre-scale); inv carries the 1/16 v pre-scale.
__global__ __launch_bounds__(256) void gather4_kernel(
    const unsigned char* __restrict__ Qb, const ushort* __restrict__ Kb,
    const int* __restrict__ rowptr, const int* __restrict__ srcs,
    ushort* __restrict__ io, float scale, int n)
{
    int i = blockIdx.x * 4 + (threadIdx.x >> 6);
    int lane = threadIdx.x & 63;
    if (i >= n) return;
    const ushort* Qu = (const ushort*)Qb;    // fp8 pairs; row stride 128 ushorts (256 B)
    const uint* Ku = (const uint*)Kb;        // row stride 64 uints

    float q0[4], q1[4];
#pragma unroll
    for (int h = 0; h < 4; ++h) {
        ushort qv = Qu[((size_t)h * NN + i) * 128 + lane];
        q0[h] = fp8lo(qv); q1[h] = fp8hi(qv);
    }
    int p0 = rowptr[i], p1 = rowptr[i + 1];
    float den[4] = {0.f, 0.f, 0.f, 0.f};
    float o0[4] = {0.f, 0.f, 0.f, 0.f};
    float o1[4] = {0.f, 0.f, 0.f, 0.f};
    int p = p0;
    for (; p + 2 <= p1; p += 2) {                 // two edges in flight
        int s0 = srcs[p], s1 = srcs[p + 1];
        uint kva = Ku[(size_t)s0 * 64 + lane];
        uint kvb = Ku[(size_t)s1 * 64 + lane];
        ushort vva[4], vvb[4];
#pragma unroll
        for (int h = 0; h < 4; ++h) vva[h] = Qu[((size_t)h * NN + s0) * 128 + 64 + lane];
#pragma unroll
        for (int h = 0; h < 4; ++h) vvb[h] = Qu[((size_t)h * NN + s1) * 128 + 64 + lane];
        float ka0 = b2f((ushort)kva), ka1 = b2f((ushort)(kva >> 16));
        float kb0 = b2f((ushort)kvb), kb1 = b2f((ushort)(kvb >> 16));
        float da[4], db[4];
#pragma unroll
        for (int h = 0; h < 4; ++h) {
            da[h] = q0[h] * ka0 + q1[h] * ka1;
            db[h] = q0[h] * kb0 + q1[h] * kb1;
        }
#pragma unroll
        for (int off = 32; off > 0; off >>= 1) {
#pragma unroll
            for (int h = 0; h < 4; ++h) {
                da[h] += __shfl_xor(da[h], off, 64);
                db[h] += __shfl_xor(db[h], off, 64);
            }
        }
#pragma unroll
        for (int h = 0; h < 4; ++h) {
            float ea = __expf(da[h] * scale);
            float eb = __expf(db[h] * scale);
            den[h] += ea + eb;
            o0[h] += ea * fp8lo(vva[h]) + eb * fp8lo(vvb[h]);
            o1[h] += ea * fp8hi(vva[h]) + eb * fp8hi(vvb[h]);
        }
    }
    if (p < p1) {                                 // tail edge
        int s = srcs[p];
        uint kv = Ku[(size_t)s * 64 + lane];
        ushort vv[4];
#pragma unroll
        for (int h = 0; h < 4; ++h) vv[h] = Qu[((size_t)h * NN + s) * 128 + 64 + lane];
        float k0 = b2f((ushort)kv), k1 = b2f((ushort)(kv >> 16));
        float d[4];
#pragma unroll
        for (int h = 0; h < 4; ++h) d[h] = q0[h] * k0 + q1[h] * k1;
#pragma unroll
        for (int off = 32; off > 0; off >>= 1) {
#pragma unroll
            for (int h = 0; h < 4; ++h) d[h] += __shfl_xor(d[h], off, 64);
        }
#pragma unroll
        for (int h = 0; h < 4; ++h) {
            float e = __expf(d[h] * scale);
            den[h] += e;
            o0[h] += e * fp8lo(vv[h]);
            o1[h] += e * fp8hi(vv[h]);
        }
    }
#pragma unroll
    for (int h = 0; h < 4; ++h) {
        uint sk = ((const uint*)io)[(size_t)i * 256 + h * 64 + lane];
        float inv = 0.0625f / (den[h] + 1e-16f);   // 1/16 undoes v pre-scale
        float r0 = fmaxf(b2f((ushort)sk) + o0[h] * inv, 0.f);
        float r1 = fmaxf(b2f((ushort)(sk >> 16)) + o1[h] * inv, 0.f);
        ((uint*)io)[(size_t)i * 256 + h * 64 + lane] = f2b_pk(r0, r1);
    }
}

// ================= conv2 gather (single head, fp8 q|k|v rows of 384 B, ILP-2) =================
// scale arg pre-divided by 256 (q,k both x16); inv carries the 1/16 v pre-scale.
__global__ __launch_bounds__(256) void edge_gather_kernel(
    const unsigned char* __restrict__ qkv,
    const int* __restrict__ rowptr, const int* __restrict__ srcs,
    const ushort* __restrict__ skip,
    ushort* __restrict__ outp, float scale, int n)
{
    int i = blockIdx.x * 4 + (threadIdx.x >> 6);
    int lane = threadIdx.x & 63;
    if (i >= n) return;
    const ushort* Qu = (const ushort*)qkv;   // fp8 pairs; row stride 192 ushorts (384 B)

    uint sk = ((const uint*)skip)[(size_t)i * 64 + lane];
    ushort qv = Qu[(size_t)i * 192 + lane];
    float q0 = fp8lo(qv), q1 = fp8hi(qv);
    int p0 = rowptr[i], p1 = rowptr[i + 1];
    float den = 0.f, o0 = 0.f, o1 = 0.f;
    int p = p0;
    for (; p + 2 <= p1; p += 2) {
        int s0 = srcs[p], s1 = srcs[p + 1];
        const ushort* kr0 = Qu + (size_t)s0 * 192 + 64;
        const ushort* kr1 = Qu + (size_t)s1 * 192 + 64;
        ushort kv0 = kr0[lane], vv0 = kr0[lane + 64];
        ushort kv1 = kr1[lane], vv1 = kr1[lane + 64];
        float d0 = q0 * fp8lo(kv0) + q1 * fp8hi(kv0);
        float d1 = q0 * fp8lo(kv1) + q1 * fp8hi(kv1);
#pragma unroll
        for (int off = 32; off > 0; off >>= 1) {
            d0 += __shfl_xor(d0, off, 64);
            d1 += __shfl_xor(d1, off, 64);
        }
        float e0 = __expf(d0 * scale), e1 = __expf(d1 * scale);
        den += e0 + e1;
        o0 += e0 * fp8lo(vv0) + e1 * fp8lo(vv1);
        o1 += e0 * fp8hi(vv0) + e1 * fp8hi(vv1);
    }
    if (p < p1) {
        int s = srcs[p];
        const ushort* kr = Qu + (size_t)s * 192 + 64;
        ushort kv = kr[lane], vv = kr[lane + 64];
        float d = q0 * fp8lo(kv) + q1 * fp8hi(kv);
#pragma unroll
        for (int off = 32; off > 0; off >>= 1) d += __shfl_xor(d, off, 64);
        float e = __expf(d * scale);
        den += e;
        o0 += e * fp8lo(vv);
        o1 += e * fp8hi(vv);
    }
    float inv = 0.0625f / (den + 1e-16f);          // 1/16 undoes v pre-scale
    float r0 = b2f((ushort)sk) + o0 * inv;
    float r1 = b2f((ushort)(sk >> 16)) + o1 * inv;
    ((uint*)outp)[(size_t)i * 64 + lane] = f2b_pk(r0, r1);
}

// ================= pool over bf16 h2: run-length partial sums (+fused relu) =================
__global__ __launch_bounds__(256) void pool_kernel(
    const ushort* __restrict__ h, const int* __restrict__ batch,
    float* __restrict__ gsum, float* __restrict__ cnt, int n)
{
    int wave = threadIdx.x >> 6, lane = threadIdx.x & 63;
    int start = blockIdx.x * 256 + wave * 64;
    int end = min(start + 64, n);
    if (start >= end) return;
    int cur = batch[start];
    float a0 = 0.f, a1 = 0.f;
    int run = 0;
    for (int node = start; node < end; ++node) {
        int g = batch[node];
        if (g != cur) {
            atomicAdd(&gsum[cur * HH + 2 * lane], a0);
            atomicAdd(&gsum[cur * HH + 2 * lane + 1], a1);
            if (lane == 0) atomicAdd(&cnt[cur], (float)run);
            cur = g; a0 = a1 = 0.f; run = 0;
        }
        uint x = ((const uint*)h)[(size_t)node * 64 + lane];
        a0 += fmaxf(b2f((ushort)x), 0.f);
        a1 += fmaxf(b2f((ushort)(x >> 16)), 0.f);
        ++run;
    }
    atomicAdd(&gsum[cur * HH + 2 * lane], a0);
    atomicAdd(&gsum[cur * HH + 2 * lane + 1], a1);
    if (lane == 0) atomicAdd(&cnt[cur], (float)run);
}

__global__ void pool_fin_kernel(const float* __restrict__ gsum,
                                const float* __restrict__ cnt, float* __restrict__ g)
{
    int i = blockIdx.x * blockDim.x + threadIdx.x;
    if (i < BB * HH) g[i] = gsum[i] / fmaxf(cnt[i / HH], 1.0f);
}

// ================= output heads =================
__global__ void out_heads_kernel(
    const float* __restrict__ g,
    const float* __restrict__ w0, const float* __restrict__ b0,
    const float* __restrict__ w1, const float* __restrict__ b1,
    const float* __restrict__ w2, const float* __restrict__ b2,
    const float* __restrict__ w3, const float* __restrict__ b3,
    const float* __restrict__ w4, const float* __restrict__ b4,
    const float* __restrict__ w5, const float* __restrict__ b5,
    const float* __restrict__ w6, const float* __restrict__ b6,
    float* __restrict__ out, int total)
{
    int t = blockIdx.x * blockDim.x + threadIdx.x;
    if (t >= total) return;
    const float* W; const float* bias; int cols; int local;
    if      (t < 64)    { W = w0; bias = b0; cols = 1;   local = t; }
    else if (t < 320)   { W = w1; bias = b1; cols = 4;   local = t - 64; }
    else if (t < 512)   { W = w2; bias = b2; cols = 3;   local = t - 320; }
    else if (t < 33280) { W = w3; bias = b3; cols = SS;  local = t - 512; }
    else if (t < 66048) { W = w4; bias = b4; cols = SS;  local = t - 33280; }
    else if (t < 98816) { W = w5; bias = b5; cols = SS;  local = t - 66048; }
    else                { W = w6; bias = b6; cols = LCC; local = t - 98816; }
    int b = local / cols, c = local % cols;
    const float* gr = g + b * HH;
    float acc = bias[c];
#pragma unroll 8
    for (int i = 0; i < HH; ++i) acc += gr[i] * W[i * cols + c];
    out[t] = acc;
}

// ================= orchestration =================
extern "C" void kernel_launch(void* const* d_in, const int* in_sizes, int n_in,
                              void* d_out, int out_size, void* d_ws, size_t ws_size,
                              hipStream_t stream)
{
    (void)in_sizes; (void)n_in; (void)out_size; (void)ws_size;

    const float* nf   = (const float*)d_in[0];
    const int*   ei   = (const int*)d_in[1];
    const int*   src  = ei;
    const int*   dst  = ei + EE;
    const int*   batch= (const int*)d_in[2];
    const float* Wp   = (const float*)d_in[3];
    const float* bp   = (const float*)d_in[4];
    const float* Wq1  = (const float*)d_in[5];
    const float* bq1  = (const float*)d_in[6];
    const float* Wk1  = (const float*)d_in[7];
    const float* bk1  = (const float*)d_in[8];
    const float* Wv1  = (const float*)d_in[9];
    const float* bv1  = (const float*)d_in[10];
    const float* Ws1  = (const float*)d_in[11];
    const float* bs1  = (const float*)d_in[12];
    const float* Wq2  = (const float*)d_in[13];
    const float* bq2  = (const float*)d_in[14];
    const float* Wk2  = (const float*)d_in[15];
    const float* bk2  = (const float*)d_in[16];
    const float* Wv2  = (const float*)d_in[17];
    const float* bv2  = (const float*)d_in[18];
    const float* Ws2  = (const float*)d_in[19];
    const float* bs2  = (const float*)d_in[20];
    const float* crW  = (const float*)d_in[21];
    const float* crb  = (const float*)d_in[22];
    const float* hlW  = (const float*)d_in[23];
    const float* hlb  = (const float*)d_in[24];
    const float* mtW  = (const float*)d_in[25];
    const float* mtb  = (const float*)d_in[26];
    const float* p1W  = (const float*)d_in[27];
    const float* p1b  = (const float*)d_in[28];
    const float* p2W  = (const float*)d_in[29];
    const float* p2b  = (const float*)d_in[30];
    const float* dtW  = (const float*)d_in[31];
    const float* dtb  = (const float*)d_in[32];
    const float* slW  = (const float*)d_in[33];
    const float* slb  = (const float*)d_in[34];
    float* out = (float*)d_out;

    (void)bk1;   // bk1 contributes only a per-dst-constant score shift (cancels in softmax)

    // ---- workspace layout (byte offsets; fp8 head/qkv buffers alias-reuse the Qb8 zone) ----
    // [0, N*1024)        Qb8   4 x N x 256 B fp8 head buffers (u|v), x16 pre-scaled
    //                    aliases: nfb (N*64 bf16, dead before F1 writes Qb8)
    //                             h2sb (N*128 bf16, step 7+) at +0
    //                             qkv8 (N*384 B fp8, step 7+) at +N*256
    //                             h2   (N*128 bf16, step 8+) at +N*640
    // [N*1024, N*1280)   h0b   N*128 bf16
    // [N*1280, N*2304)   h1b   N*512 bf16 (conv1 skip AND out, in-place)
    // then wt | bb | CSR ints | pool buffers
    unsigned char* base = (unsigned char*)d_ws;
    unsigned char* Qb8  = base;
    ushort* nfb  = (ushort*)base;
    ushort* h2sb = (ushort*)base;
    unsigned char* qkv8 = base + (size_t)NN * 256;
    ushort* h2   = (ushort*)(base + (size_t)NN * 640);
    ushort* h0b  = (ushort*)(base + (size_t)NN * 1024);
    ushort* h1b  = (ushort*)(base + (size_t)NN * 1280);
    ushort* wt   = (ushort*)(base + (size_t)NN * 2304);
    float*  bb   = (float*)(wt + WTOTAL);
    int*    rowptr = (int*)(bb + BTOT);                    // N+1
    int*    srcs   = rowptr + NN + 1;                      // E
    int*    cnt    = srcs + EE;                            // N
    float*  gsum   = (float*)(cnt + NN);                   // B*128
    float*  cntb   = gsum + BB * HH;                       // B
    int*    cursor = (int*)(cntb + BB);                    // N
    int*    bsum   = cursor + NN;                          // 64
    float*  gbuf   = (float*)(bsum + 64);                  // B*128

    const float scale = 0.08838834764831845f; // 1/sqrt(128)
    const dim3 blk(256);
    const int gy  = (NN + BM - 1) / BM;         // 391 row-blocks
    const int gyp = ((gy + 7) / 8) * 8;         // 392 (XCD-padded)
    const int nb = (NN + SCAN_B - 1) / SCAN_B;  // 49

    // 1) weight prep + bilinear M/r composition (fused, fp8 pre-scales folded)
    prep_kernel<<<(WTOTAL + BTOT + MWORK + 255) / 256, blk, 0, stream>>>(
        Wp, Wq1, Wk1, Wv1, Ws1, Wq2, Wk2, Wv2, Ws2,
        bs1, bq1, bv1, bs2, bq2, bk2, bv2, wt, bb);

    // 2) nf -> bf16
    f32_to_bf16_kernel<<<((NN * FF / 4) + 255) / 256, blk, 0, stream>>>(
        (const float4*)nf, (uint2*)nfb, NN * FF / 4);

    // 3) CSR build (scan_excl fused into scan_final)
    fill_kernel<<<(NN + BB * HH + BB + 255) / 256, blk, 0, stream>>>(
        (unsigned*)cnt, 0u, NN + BB * HH + BB);
    hist_kernel<<<(EE + 255) / 256, blk, 0, stream>>>(dst, cnt, EE);
    scan_bsum_kernel<<<nb, blk, 0, stream>>>(cnt, bsum, NN);
    scan_final_kernel<<<nb, blk, 0, stream>>>(cnt, bsum, rowptr, cursor, NN);
    bucket_kernel<<<(EE + 255) / 256, blk, 0, stream>>>(src, dst, cursor, srcs, EE);

    // 4) proj: h0b = relu(nf @ Wp + bp)   (mode 0, gx=1, K=64)
    gemm_bf16<<<dim3(1 * gyp), blk, 0, stream>>>(
        nfb, wt, bp, h0b, HH, h0b, 0, NN, FF, 1, 1, gy);

    // 5) F1-mega: [skip(512)->h1b bf16 | per head u|v -> Qb8 fp8]   (mode 1, gx=12, K=128)
    gemm_bf16<<<dim3(12 * gyp), blk, 0, stream>>>(
        h0b, wt + F1OFF, bb, h1b, 512, (ushort*)Qb8, 1, NN, HH, 0, 12, gy);

    // 6) fused 4-head gather (fp8 u/v; scale/16 for u pre-scale)
    gather4_kernel<<<(NN + 3) / 4, blk, 0, stream>>>(
        Qb8, h0b, rowptr, srcs, h1b, scale * 0.0625f, NN);

    // 7) F2: [skip(128)->h2sb bf16 | qkv(384)->qkv8 fp8]   (mode 2, gx=4, K=512)
    gemm_bf16<<<dim3(4 * gyp), blk, 0, stream>>>(
        h1b, wt + F2OFF, bb + 1536, h2sb, 128, (ushort*)qkv8, 2, NN, 4 * HH, 0, 4, gy);

    // 8) gather conv2 (fp8 q/k/v; scale/256 for q,k pre-scales)
    edge_gather_kernel<<<(NN + 3) / 4, blk, 0, stream>>>(
        qkv8, rowptr, srcs, h2sb, h2, scale * 0.00390625f, NN);

    // 9) pool (relu fused, bf16 input) + finalize
    pool_kernel<<<(NN + 255) / 256, blk, 0, stream>>>(h2, batch, gsum, cntb, NN);
    pool_fin_kernel<<<(BB * HH + 255) / 256, blk, 0, stream>>>(gsum, cntb, gbuf);

    // 10) output heads
    const int total = BB * (1 + 4 + 3 + SS + SS + SS + LCC);
    out_heads_kernel<<<(total + 255) / 256, blk, 0, stream>>>(
        gbuf, crW, crb, hlW, hlb, mtW, mtb, p1W, p1b, p2W, p2b, dtW, dtb, slW, slb, out, total);
}

// Round 2
// 330.469 us; speedup vs baseline: 1.1201x; 1.0275x over previous
//
#include <hip/hip_runtime.h>
#include <hip/hip_bf16.h>

#define NN 50000
#define EE 100000
#define FF 64
#define HH 128
#define HEADS 4
#define BB 64
#define SS 512
#define LCC 8

// ---- bf16 helpers ----
__device__ __forceinline__ float b2f(ushort u) {
    return __uint_as_float(((unsigned)u) << 16);
}
__device__ __forceinline__ ushort f2b(float f) {
    unsigned u = __float_as_uint(f);
    unsigned r = (u + 0x7FFFu + ((u >> 16) & 1u)) >> 16;   // RNE
    return (ushort)r;
}
// packed RNE convert: 2 f32 -> 1 uint (low = a), maps to v_cvt_pk_bf16_f32
__device__ __forceinline__ uint f2b_pk(float a, float b) {
    __hip_bfloat162 h = __float22bfloat162_rn(make_float2(a, b));
    return *reinterpret_cast<uint*>(&h);
}

// ---- fp8 (OCP e4m3fn) helpers: HW cvt on gfx950 ----
// values are stored pre-scaled x16 to stay in the normal range (sigma ~0.006-0.04)
__device__ __forceinline__ uint f2fp8x4(float a, float b, float c, float d) {
    int r = __builtin_amdgcn_cvt_pk_fp8_f32(a, b, 0, false);   // bytes 0,1
    r = __builtin_amdgcn_cvt_pk_fp8_f32(c, d, r, true);        // bytes 2,3
    return (uint)r;
}
// 4 fp8 bytes -> 4 f32 via two packed HW converts
__device__ __forceinline__ void fp8x4(uint u, float* f) {
    auto lo = __builtin_amdgcn_cvt_pk_f32_fp8((int)u, false);
    auto hi = __builtin_amdgcn_cvt_pk_f32_fp8((int)u, true);
    f[0] = lo[0]; f[1] = lo[1]; f[2] = hi[0]; f[3] = hi[1];
}

typedef __attribute__((ext_vector_type(4))) float f32x4;
typedef __attribute__((ext_vector_type(8))) short s16x8;
typedef __attribute__((ext_vector_type(4))) uint u32x4;

__device__ __forceinline__ void glls16(const ushort* g, ushort* l) {
    __builtin_amdgcn_global_load_lds((const __attribute__((address_space(1))) void*)g,
                                     (__attribute__((address_space(3))) void*)l, 16, 0, 0);
}

// ================= bf16 MFMA GEMM (r12-proven core; bf16 or fp8 epilogue) =================
#define BM 128
#define BN 128
#define BK 64
#define EST 68   // epilogue staging stride (f32) — breaks power-of-2 bank aliasing

__global__ __launch_bounds__(256) void gemm_bf16(
    const ushort* __restrict__ A, const ushort* __restrict__ Bt,
    const float* __restrict__ bias,
    ushort* __restrict__ C1, int ld1,
    ushort* __restrict__ C2b, int mode,
    int M, int K, int relu, int gx, int gy)
{
    __shared__ __align__(16) ushort Sm[2 * BM * BK];   // 32 KB: As | Bs, reused by epilogue
    ushort* As = Sm;
    ushort* Bs = Sm + BM * BK;

    const int bid  = blockIdx.x;
    const int xcd  = bid & 7;
    const int slot = bid >> 3;
    const int bx   = slot % gx;
    const int by   = xcd + 8 * (slot / gx);
    if (by >= gy) return;
    const int m0 = by * BM;
    const int n0 = bx * BN;

    const int t = threadIdx.x;
    const int lane = t & 63;
    const int wave = t >> 6;
    const int wm = (wave & 1) * 64;
    const int wn = (wave >> 1) * 64;
    const int lrow = lane & 15;
    const int g    = lane >> 4;

    const int wbase = n0 + wn;
    float bj[4];
#pragma unroll
    for (int j = 0; j < 4; ++j) bj[j] = bias[wbase + j * 16 + lrow];

    const int srow = (wave << 5) + (lane >> 3);
    const int scs  = lane & 7;

    const ushort* ga[4];
    const ushort* gb[4];
#pragma unroll
    for (int p = 0; p < 4; ++p) {
        const int row = srow + (p << 3);
        const int l   = scs ^ (row & 7);
        ga[p] = A + (size_t)min(m0 + row, M - 1) * K + (l << 3);
        gb[p] = Bt + (size_t)(n0 + row) * K + (l << 3);
    }
    const int ldsoff = (wave << 11);

    // bias folded into acc init
    f32x4 acc[4][4];
#pragma unroll
    for (int i = 0; i < 4; ++i)
#pragma unroll
        for (int j = 0; j < 4; ++j)
            acc[i][j] = (f32x4){bj[j], bj[j], bj[j], bj[j]};

    for (int k0 = 0; k0 < K; k0 += BK) {
#pragma unroll
        for (int p = 0; p < 4; ++p) glls16(ga[p] + k0, As + ldsoff + (p << 9));
#pragma unroll
        for (int p = 0; p < 4; ++p) glls16(gb[p] + k0, Bs + ldsoff + (p << 9));
        __syncthreads();

#pragma unroll
        for (int kk = 0; kk < 2; ++kk) {
            s16x8 af[4], bf[4];
#pragma unroll
            for (int i = 0; i < 4; ++i) {
                const int R = wm + i * 16 + lrow;
                const int c = ((kk << 2) + g) ^ (R & 7);
                af[i] = *(const s16x8*)&As[(R << 6) + (c << 3)];
            }
#pragma unroll
            for (int j = 0; j < 4; ++j) {
                const int R = wn + j * 16 + lrow;
                const int c = ((kk << 2) + g) ^ (R & 7);
                bf[j] = *(const s16x8*)&Bs[(R << 6) + (c << 3)];
            }
#pragma unroll
            for (int i = 0; i < 4; ++i)
#pragma unroll
                for (int j = 0; j < 4; ++j)
                    acc[i][j] = __builtin_amdgcn_mfma_f32_16x16x32_bf16(af[i], bf[j], acc[i][j], 0, 0, 0);
        }
        __syncthreads();
    }

    // ---- LDS-staged epilogue (bf16 or fp8 stream per wave) ----
    float* Es = (float*)Sm + wave * (16 * EST);

    bool e8 = false;
    ushort* Cw = C1; int ldw = ld1; int cb = wbase;
    unsigned char* Cw8 = nullptr;
    if (mode == 1) {
        e8 = true;
        if (wbase < 512) {                    // fp8 skip buffer (x16 folded into Ws1/bs1)
            Cw8 = (unsigned char*)C1;
            ldw = 512;
        } else {                              // per-head u|v buffer, fp8 rows of 256 B
            const int u = wbase - 512;
            const int h = u >> 8;
            cb = u & 255;
            Cw8 = (unsigned char*)C2b + (size_t)h * NN * 256;
            ldw = 256;
        }
    } else if (mode == 2) {
        if (wbase < 128) { ldw = 128; }
        else {                                // q|k|v buffer, fp8 rows of 384 B
            e8 = true;
            Cw8 = (unsigned char*)C2b;
            ldw = 384;
            cb = wbase - 128;
        }
    }

    const int rbase = (lane >> 4) * 4;
    const int rrow  = lane >> 2;
    const int rcol  = (lane & 3) << 4;

#pragma unroll
    for (int i = 0; i < 4; ++i) {
#pragma unroll
        for (int j = 0; j < 4; ++j)
#pragma unroll
            for (int r = 0; r < 4; ++r) {
                float v = acc[i][j][r];
                if (relu) v = fmaxf(v, 0.f);
                Es[(rbase + r) * EST + j * 16 + lrow] = v;
            }
        const int gm = m0 + wm + i * 16 + rrow;
        if (gm < M) {
            const float* srcp = Es + rrow * EST + rcol;
            f32x4 f0 = *(const f32x4*)(srcp + 0);
            f32x4 f1 = *(const f32x4*)(srcp + 4);
            f32x4 f2 = *(const f32x4*)(srcp + 8);
            f32x4 f3 = *(const f32x4*)(srcp + 12);
            if (!e8) {
                u32x4 o0, o1;
                o0[0] = f2b_pk(f0[0], f0[1]); o0[1] = f2b_pk(f0[2], f0[3]);
                o0[2] = f2b_pk(f1[0], f1[1]); o0[3] = f2b_pk(f1[2], f1[3]);
                o1[0] = f2b_pk(f2[0], f2[1]); o1[1] = f2b_pk(f2[2], f2[3]);
                o1[2] = f2b_pk(f3[0], f3[1]); o1[3] = f2b_pk(f3[2], f3[3]);
                ushort* dst = Cw + (size_t)gm * ldw + cb + rcol;
                *(u32x4*)(dst + 0) = o0;
                *(u32x4*)(dst + 8) = o1;
            } else {
                u32x4 o;
                o[0] = f2fp8x4(f0[0], f0[1], f0[2], f0[3]);
                o[1] = f2fp8x4(f1[0], f1[1], f1[2], f1[3]);
                o[2] = f2fp8x4(f2[0], f2[1], f2[2], f2[3]);
                o[3] = f2fp8x4(f3[0], f3[1], f3[2], f3[3]);
                *(u32x4*)(Cw8 + (size_t)gm * ldw + cb + rcol) = o;
            }
        }
    }
}

// ================= weight prep + mcomp fused (disjoint writes) =================
// wt layout (rows [n][k], bf16):
//  [0, 8192)            Wpt   [128][64]
//  [8192, 204800)       F1    [1536][128] = 16*Ws1t(512) | per head: u(128, 16*M) | v(128, 16*Wv1)
//  [204800, 466944)     F2    [512][512]  = Ws2t(128) | 16*(q2|k2|v2) (384)
// bb: [0,512) 16*bs1; per head [512+h*256,+128) 16*r_h, [+128,+256) 16*bv1; [1536,2048) F2
//     (F2: bs2 | 16*bq2 | 16*bk2 | 16*bv2)
// fp8 streams are stored x16 pre-scaled; gathers divide back out.
#define F1OFF  8192
#define F2OFF  204800
#define WTOTAL 466944
#define BTOT   2048
#define MWORK  (HEADS * 128 * 128 + HEADS * 128)   // 66048

__global__ void prep_kernel(
    const float* __restrict__ Wp,
    const float* __restrict__ Wq1, const float* __restrict__ Wk1,
    const float* __restrict__ Wv1, const float* __restrict__ Ws1,
    const float* __restrict__ Wq2, const float* __restrict__ Wk2,
    const float* __restrict__ Wv2, const float* __restrict__ Ws2,
    const float* __restrict__ bs1, const float* __restrict__ bq1,
    const float* __restrict__ bv1, const float* __restrict__ bs2,
    const float* __restrict__ bq2, const float* __restrict__ bk2, const float* __restrict__ bv2,
    ushort* __restrict__ wt, float* __restrict__ bb)
{
    int t = blockIdx.x * 256 + threadIdx.x;
    if (t < WTOTAL) {
        float v;
        if (t < F1OFF) {
            int n = t >> 6, k = t & 63;
            v = Wp[k * 128 + n];
        } else if (t < F2OFF) {
            int u = t - F1OFF;
            int n = u >> 7, k = u & 127;
            if (n < 512) v = Ws1[k * 512 + n] * 16.0f;        // fp8 skip pre-scale
            else {
                int r = n - 512;
                int h = r >> 8, c = r & 255;
                if (c < 128) return;             // u (M) rows: filled by mcomp branch
                v = Wv1[k * 512 + h * 128 + (c - 128)] * 16.0f;
            }
        } else {
            int u = t - F2OFF;
            int n = u >> 9, k = u & 511;
            if (n < 128) v = Ws2[k * 128 + n];
            else {
                int r = n - 128;
                const float* W = (r < 128) ? Wq2 : (r < 256) ? Wk2 : Wv2;
                v = W[k * 128 + (r & 127)] * 16.0f;
            }
        }
        wt[t] = f2b(v);
    } else if (t < WTOTAL + BTOT) {
        int u = t - WTOTAL;
        float v;
        if (u < 512) v = bs1[u] * 16.0f;                      // fp8 skip pre-scale
        else if (u < 1536) {
            int r = u - 512;
            int h = r >> 8, c = r & 255;
            if (c < 128) return;                 // r_h bias: filled by mcomp branch
            v = bv1[h * 128 + (c - 128)] * 16.0f;
        } else {
            int c = u - 1536;
            v = (c < 128) ? bs2[c]
              : (c < 256) ? bq2[c - 128] * 16.0f
              : (c < 384) ? bk2[c - 256] * 16.0f : bv2[c - 384] * 16.0f;
        }
        bb[u] = v;
    } else if (t < WTOTAL + BTOT + MWORK) {
        int m = t - (WTOTAL + BTOT);
        if (m < HEADS * 128 * 128) {             // M_h[a][b] = Wq_h[:,a] . Wk_h[:,b]
            int h = m >> 14;
            int rem = m & 16383;
            int b = rem >> 7, a = rem & 127;
            const float* wq = Wq1 + a * 512 + h * 128;
            const float* wk = Wk1 + b * 512 + h * 128;
            float acc = 0.f;
#pragma unroll 8
            for (int d = 0; d < 128; ++d) acc += wq[d] * wk[d];
            wt[F1OFF + (size_t)(512 + h * 256 + b) * 128 + a] = f2b(acc * 16.0f);
        } else {                                 // r_h[b] = Wk_h[:,b] . bq_h
            int u = m - HEADS * 128 * 128;
            int h = u >> 7, b = u & 127;
            const float* wk = Wk1 + b * 512 + h * 128;
            const float* bq = bq1 + h * 128;
            float acc = 0.f;
#pragma unroll 8
            for (int d = 0; d < 128; ++d) acc += wk[d] * bq[d];
            bb[512 + h * 256 + b] = acc * 16.0f;
        }
    }
}

// ================= fp32 -> bf16 (x4, packed cvt) + fused zero-fill =================
__global__ void cvt_fill_kernel(const float4* __restrict__ in, uint2* __restrict__ out, int n4,
                                unsigned* __restrict__ fillp, int filln)
{
    int i = blockIdx.x * 256 + threadIdx.x;
    if (i < n4) {
        float4 v = in[i];
        uint2 o;
        o.x = f2b_pk(v.x, v.y);
        o.y = f2b_pk(v.z, v.w);
        out[i] = o;
    } else {
        int j = i - n4;
        if (j < filln) fillp[j] = 0u;
    }
}

// ================= CSR build (dst -> src list) =================
__global__ void hist_kernel(const int* __restrict__ dst, int* __restrict__ cnt, int E) {
    int e = blockIdx.x * 256 + threadIdx.x;
    if (e < E) atomicAdd(&cnt[dst[e]], 1);
}

#define SCAN_B 1024
__global__ void scan_bsum_kernel(const int* __restrict__ cnt, int* __restrict__ bsum, int n) {
    __shared__ int sd[256];
    int tid = threadIdx.x;
    int base = blockIdx.x * SCAN_B + tid * 4;
    int s = 0;
#pragma unroll
    for (int j = 0; j < 4; ++j) if (base + j < n) s += cnt[base + j];
    sd[tid] = s;
    __syncthreads();
    for (int off = 128; off > 0; off >>= 1) {
        if (tid < off) sd[tid] += sd[tid + off];
        __syncthreads();
    }
    if (tid == 0) bsum[blockIdx.x] = sd[0];
}

// scan_final with fused exclusive block-prefix (reads RAW bsum; no scan_excl pass)
__global__ void scan_final_kernel(const int* __restrict__ cnt, const int* __restrict__ bsum,
                                  int* __restrict__ rowptr, int* __restrict__ cursor, int n) {
    __shared__ int sd[256];
    __shared__ int sb[256];
    int tid = threadIdx.x;
    sb[tid] = (tid < blockIdx.x) ? bsum[tid] : 0;
    __syncthreads();
    for (int off = 128; off > 0; off >>= 1) {
        if (tid < off) sb[tid] += sb[tid + off];
        __syncthreads();
    }
    const int bbase = sb[0];

    int base = blockIdx.x * SCAN_B + tid * 4;
    int v[4]; int s = 0;
#pragma unroll
    for (int j = 0; j < 4; ++j) { v[j] = (base + j < n) ? cnt[base + j] : 0; s += v[j]; }
    sd[tid] = s;
    __syncthreads();
    for (int off = 1; off < 256; off <<= 1) {
        int t2 = (tid >= off) ? sd[tid - off] : 0;
        __syncthreads();
        sd[tid] += t2;
        __syncthreads();
    }
    int acc = bbase + sd[tid] - s;
#pragma unroll
    for (int j = 0; j < 4; ++j) {
        if (base + j < n) cursor[base + j] = acc;
        acc += v[j];
        if (base + j < n) rowptr[base + j + 1] = acc;
    }
    if (blockIdx.x == 0 && tid == 0) rowptr[0] = 0;
}

__global__ void bucket_kernel(const int* __restrict__ src, const int* __restrict__ dst,
                              int* __restrict__ cursor, int* __restrict__ srcs, int E) {
    int e = blockIdx.x * 256 + threadIdx.x;
    if (e >= E) return;
    int p = atomicAdd(&cursor[dst[e]], 1);
    srcs[p] = src[e];
}

// ================= conv1 gather: 16 LANES PER HEAD (4 head-groups/wave), ILP-2 =================
// Lane = h*16 + l; lane handles dims [l*8, l*8+8) of head h.
// Qb: 4 fp8 head buffers (stride NN*256 B), row = [u(128)|v(128)] fp8, x16 pre-scaled.
// Kb: h0 rows (128 bf16) — all 4 groups read the same 16 B (broadcast-friendly).
// s8: fp8 skip rows [N][512], x16 pre-scaled. outp: h1b bf16 [N][512], write-only.
// score reduce = 4 shfl levels within the 16-lane group; no cross-group reduce needed
// (heads are independent, disjoint output channels).
__global__ __launch_bounds__(256) void gather4_kernel(
    const unsigned char* __restrict__ Qb, const ushort* __restrict__ Kb,
    const int* __restrict__ rowptr, const int* __restrict__ srcs,
    const unsigned char* __restrict__ s8,
    ushort* __restrict__ outp, float scale, int n)
{
    int i = blockIdx.x * 4 + (threadIdx.x >> 6);
    int lane = threadIdx.x & 63;
    if (i >= n) return;
    const int h = lane >> 4;
    const int l = lane & 15;

    const unsigned char* Qh = Qb + (size_t)h * ((size_t)NN * 256);

    uint2 uq = *(const uint2*)(Qh + (size_t)i * 256 + l * 8);
    float q[8];
    fp8x4(uq.x, q); fp8x4(uq.y, q + 4);

    int p0 = rowptr[i], p1 = rowptr[i + 1];
    float den = 0.f;
    float o[8] = {0.f, 0.f, 0.f, 0.f, 0.f, 0.f, 0.f, 0.f};
    int p = p0;
    for (; p + 2 <= p1; p += 2) {                 // two edges in flight
        int s0 = srcs[p], s1 = srcs[p + 1];
        s16x8 ka = *(const s16x8*)(Kb + (size_t)s0 * 128 + l * 8);
        s16x8 kb = *(const s16x8*)(Kb + (size_t)s1 * 128 + l * 8);
        uint2 va = *(const uint2*)(Qh + (size_t)s0 * 256 + 128 + l * 8);
        uint2 vb = *(const uint2*)(Qh + (size_t)s1 * 256 + 128 + l * 8);
        float da = 0.f, db = 0.f;
#pragma unroll
        for (int d = 0; d < 8; ++d) {
            da += q[d] * b2f((ushort)ka[d]);
            db += q[d] * b2f((ushort)kb[d]);
        }
#pragma unroll
        for (int off = 8; off > 0; off >>= 1) {
            da += __shfl_xor(da, off, 64);
            db += __shfl_xor(db, off, 64);
        }
        float ea = __expf(da * scale);
        float eb = __expf(db * scale);
        den += ea + eb;
        float fa[8], fb[8];
        fp8x4(va.x, fa); fp8x4(va.y, fa + 4);
        fp8x4(vb.x, fb); fp8x4(vb.y, fb + 4);
#pragma unroll
        for (int d = 0; d < 8; ++d) o[d] += ea * fa[d] + eb * fb[d];
    }
    if (p < p1) {                                 // tail edge
        int s = srcs[p];
        s16x8 kv = *(const s16x8*)(Kb + (size_t)s * 128 + l * 8);
        uint2 vv = *(const uint2*)(Qh + (size_t)s * 256 + 128 + l * 8);
        float d0 = 0.f;
#pragma unroll
        for (int d = 0; d < 8; ++d) d0 += q[d] * b2f((ushort)kv[d]);
#pragma unroll
        for (int off = 8; off > 0; off >>= 1) d0 += __shfl_xor(d0, off, 64);
        float e = __expf(d0 * scale);
        den += e;
        float fv[8];
        fp8x4(vv.x, fv); fp8x4(vv.y, fv + 4);
#pragma unroll
        for (int d = 0; d < 8; ++d) o[d] += e * fv[d];
    }
    // epilogue: r = relu(skip + attn); skip and v both x16 -> single 1/16 after relu
    float invd = 1.0f / (den + 1e-16f);
    uint2 sk = *(const uint2*)(s8 + (size_t)i * 512 + h * 128 + l * 8);
    float skf[8];
    fp8x4(sk.x, skf); fp8x4(sk.y, skf + 4);
    float r[8];
#pragma unroll
    for (int d = 0; d < 8; ++d) r[d] = 0.0625f * fmaxf(skf[d] + o[d] * invd, 0.f);
    u32x4 ov;
    ov[0] = f2b_pk(r[0], r[1]);
    ov[1] = f2b_pk(r[2], r[3]);
    ov[2] = f2b_pk(r[4], r[5]);
    ov[3] = f2b_pk(r[6], r[7]);
    *(u32x4*)(outp + (size_t)i * 512 + h * 128 + l * 8) = ov;
}

// ================= conv2 gather: 4 EDGE-GROUPS x 16 lanes =================
// Lane = g*16 + l; group g handles edges p0+4t+g; lane covers channels [l*8, l*8+8).
// qkv rows [q(128)|k(128)|v(128)] fp8, x16 pre-scaled. Cross-group combine (den, o[8])
// via 2 shfl levels at the end; write predicated on group 0.
__global__ __launch_bounds__(256) void edge_gather_kernel(
    const unsigned char* __restrict__ qkv,
    const int* __restrict__ rowptr, const int* __restrict__ srcs,
    const ushort* __restrict__ skip,
    ushort* __restrict__ outp, float scale, int n)
{
    int i = blockIdx.x * 4 + (threadIdx.x >> 6);
    int lane = threadIdx.x & 63;
    if (i >= n) return;
    const int g = lane >> 4;
    const int l = lane & 15;

    uint2 uq = *(const uint2*)(qkv + (size_t)i * 384 + l * 8);
    float q[8];
    fp8x4(uq.x, q); fp8x4(uq.y, q + 4);

    int p0 = rowptr[i], p1 = rowptr[i + 1];
    float den = 0.f;
    float o[8] = {0.f, 0.f, 0.f, 0.f, 0.f, 0.f, 0.f, 0.f};
    for (int pb = p0; pb < p1; pb += 4) {
        int p = pb + g;
        bool act = p < p1;
        int s = srcs[act ? p : p0];
        const unsigned char* row = qkv + (size_t)s * 384;
        uint2 kv = *(const uint2*)(row + 128 + l * 8);
        uint2 vv = *(const uint2*)(row + 256 + l * 8);
        float kf[8];
        fp8x4(kv.x, kf); fp8x4(kv.y, kf + 4);
        float d0 = 0.f;
#pragma unroll
        for (int d = 0; d < 8; ++d) d0 += q[d] * kf[d];
#pragma unroll
        for (int off = 8; off > 0; off >>= 1) d0 += __shfl_xor(d0, off, 64);
        float e = act ? __expf(d0 * scale) : 0.f;
        den += e;
        float vf[8];
        fp8x4(vv.x, vf); fp8x4(vv.y, vf + 4);
#pragma unroll
        for (int d = 0; d < 8; ++d) o[d] += e * vf[d];
    }
    // combine the 4 edge-groups (same channels in every group)
#pragma unroll
    for (int off = 16; off < 64; off <<= 1) {
        den += __shfl_xor(den, off, 64);
#pragma unroll
        for (int d = 0; d < 8; ++d) o[d] += __shfl_xor(o[d], off, 64);
    }
    if (g == 0) {
        float inv = 0.0625f / (den + 1e-16f);      // 1/16 undoes v pre-scale
        s16x8 sk = *(const s16x8*)(skip + (size_t)i * 128 + l * 8);
        float r[8];
#pragma unroll
        for (int d = 0; d < 8; ++d) r[d] = b2f((ushort)sk[d]) + o[d] * inv;
        u32x4 ov;
        ov[0] = f2b_pk(r[0], r[1]);
        ov[1] = f2b_pk(r[2], r[3]);
        ov[2] = f2b_pk(r[4], r[5]);
        ov[3] = f2b_pk(r[6], r[7]);
        *(u32x4*)(outp + (size_t)i * 128 + l * 8) = ov;
    }
}

// ================= pool over bf16 h2: run-length partial sums (+fused relu) =================
__global__ __launch_bounds__(256) void pool_kernel(
    const ushort* __restrict__ h, const int* __restrict__ batch,
    float* __restrict__ gsum, float* __restrict__ cnt, int n)
{
    int wave = threadIdx.x >> 6, lane = threadIdx.x & 63;
    int start = blockIdx.x * 256 + wave * 64;
    int end = min(start + 64, n);
    if (start >= end) return;
    int cur = batch[start];
    float a0 = 0.f, a1 = 0.f;
    int run = 0;
    for (int node = start; node < end; ++node) {
        int g = batch[node];
        if (g != cur) {
            atomicAdd(&gsum[cur * HH + 2 * lane], a0);
            atomicAdd(&gsum[cur * HH + 2 * lane + 1], a1);
            if (lane == 0) atomicAdd(&cnt[cur], (float)run);
            cur = g; a0 = a1 = 0.f; run = 0;
        }
        uint x = ((const uint*)h)[(size_t)node * 64 + lane];
        a0 += fmaxf(b2f((ushort)x), 0.f);
        a1 += fmaxf(b2f((ushort)(x >> 16)), 0.f);
        ++run;
    }
    atomicAdd(&gsum[cur * HH + 2 * lane], a0);
    atomicAdd(&gsum[cur * HH + 2 * lane + 1], a1);
    if (lane == 0) atomicAdd(&cnt[cur], (float)run);
}

__global__ void pool_fin_kernel(const float* __restrict__ gsum,
                                const float* __restrict__ cnt, float* __restrict__ g)
{
    int i = blockIdx.x * blockDim.x + threadIdx.x;
    if (i < BB * HH) g[i] = gsum[i] / fmaxf(cnt[i / HH], 1.0f);
}

// ================= output heads =================
__global__ void out_heads_kernel(
    const float* __restrict__ g,
    const float* __restrict__ w0, const float* __restrict__ b0,
    const float* __restrict__ w1, const float* __restrict__ b1,
    const float* __restrict__ w2, const float* __restrict__ b2,
    const float* __restrict__ w3, const float* __restrict__ b3,
    const float* __restrict__ w4, const float* __restrict__ b4,
    const float* __restrict__ w5, const float* __restrict__ b5,
    const float* __restrict__ w6, const float* __restrict__ b6,
    float* __restrict__ out, int total)
{
    int t = blockIdx.x * blockDim.x + threadIdx.x;
    if (t >= total) return;
    const float* W; const float* bias; int cols; int local;
    if      (t < 64)    { W = w0; bias = b0; cols = 1;   local = t; }
    else if (t < 320)   { W = w1; bias = b1; cols = 4;   local = t - 64; }
    else if (t < 512)   { W = w2; bias = b2; cols = 3;   local = t - 320; }
    else if (t < 33280) { W = w3; bias = b3; cols = SS;  local = t - 512; }
    else if (t < 66048) { W = w4; bias = b4; cols = SS;  local = t - 33280; }
    else if (t < 98816) { W = w5; bias = b5; cols = SS;  local = t - 66048; }
    else                { W = w6; bias = b6; cols = LCC; local = t - 98816; }
    int b = local / cols, c = local % cols;
    const float* gr = g + b * HH;
    float acc = bias[c];
#pragma unroll 8
    for (int i = 0; i < HH; ++i) acc += gr[i] * W[i * cols + c];
    out[t] = acc;
}

// ================= orchestration =================
extern "C" void kernel_launch(void* const* d_in, const int* in_sizes, int n_in,
                              void* d_out, int out_size, void* d_ws, size_t ws_size,
                              hipStream_t stream)
{
    (void)in_sizes; (void)n_in; (void)out_size; (void)ws_size;

    const float* nf   = (const float*)d_in[0];
    const int*   ei   = (const int*)d_in[1];
    const int*   src  = ei;
    const int*   dst  = ei + EE;
    const int*   batch= (const int*)d_in[2];
    const float* Wp   = (const float*)d_in[3];
    const float* bp   = (const float*)d_in[4];
    const float* Wq1  = (const float*)d_in[5];
    const float* bq1  = (const float*)d_in[6];
    const float* Wk1  = (const float*)d_in[7];
    const float* bk1  = (const float*)d_in[8];
    const float* Wv1  = (const float*)d_in[9];
    const float* bv1  = (const float*)d_in[10];
    const float* Ws1  = (const float*)d_in[11];
    const float* bs1  = (const float*)d_in[12];
    const float* Wq2  = (const float*)d_in[13];
    const float* bq2  = (const float*)d_in[14];
    const float* Wk2  = (const float*)d_in[15];
    const float* bk2  = (const float*)d_in[16];
    const float* Wv2  = (const float*)d_in[17];
    const float* bv2  = (const float*)d_in[18];
    const float* Ws2  = (const float*)d_in[19];
    const float* bs2  = (const float*)d_in[20];
    const float* crW  = (const float*)d_in[21];
    const float* crb  = (const float*)d_in[22];
    const float* hlW  = (const float*)d_in[23];
    const float* hlb  = (const float*)d_in[24];
    const float* mtW  = (const float*)d_in[25];
    const float* mtb  = (const float*)d_in[26];
    const float* p1W  = (const float*)d_in[27];
    const float* p1b  = (const float*)d_in[28];
    const float* p2W  = (const float*)d_in[29];
    const float* p2b  = (const float*)d_in[30];
    const float* dtW  = (const float*)d_in[31];
    const float* dtb  = (const float*)d_in[32];
    const float* slW  = (const float*)d_in[33];
    const float* slb  = (const float*)d_in[34];
    float* out = (float*)d_out;

    (void)bk1;   // bk1 contributes only a per-dst-constant score shift (cancels in softmax)

    // ---- workspace layout (byte offsets) ----
    // [0, N*1024)          Qb8  4 x N x 256 B fp8 head buffers (u|v), x16
    //                      aliases: nfb (N*128 B bf16, dead before F1)
    //                               h2sb (N*256 B bf16, step 7+) at +0
    //                               qkv8 (N*384 B fp8, step 7+) at +N*256
    //                               h2   (N*256 B bf16, step 8+) at +N*640
    // [N*1024, N*1280)     h0b  N*128 bf16
    // [N*1280, N*2304)     h1b  N*512 bf16 (gather4 out, F2 A)
    // [N*2304, N*2816)     s8   N*512 fp8 skip (F1 out, gather4 in), x16
    // [N*2816, ...)        wt | bb | CSR ints | pool buffers
    unsigned char* base = (unsigned char*)d_ws;
    unsigned char* Qb8  = base;
    ushort* nfb  = (ushort*)base;
    ushort* h2sb = (ushort*)base;
    unsigned char* qkv8 = base + (size_t)NN * 256;
    ushort* h2   = (ushort*)(base + (size_t)NN * 640);
    ushort* h0b  = (ushort*)(base + (size_t)NN * 1024);
    ushort* h1b  = (ushort*)(base + (size_t)NN * 1280);
    unsigned char* s8 = base + (size_t)NN * 2304;
    ushort* wt   = (ushort*)(base + (size_t)NN * 2816);
    float*  bb   = (float*)(wt + WTOTAL);
    int*    rowptr = (int*)(bb + BTOT);                    // N+1
    int*    srcs   = rowptr + NN + 1;                      // E
    int*    cnt    = srcs + EE;                            // N
    float*  gsum   = (float*)(cnt + NN);                   // B*128
    float*  cntb   = gsum + BB * HH;                       // B
    int*    cursor = (int*)(cntb + BB);                    // N
    int*    bsum   = cursor + NN;                          // 64
    float*  gbuf   = (float*)(bsum + 64);                  // B*128

    const float scale = 0.08838834764831845f; // 1/sqrt(128)
    const dim3 blk(256);
    const int gy  = (NN + BM - 1) / BM;         // 391 row-blocks
    const int gyp = ((gy + 7) / 8) * 8;         // 392 (XCD-padded)
    const int nb = (NN + SCAN_B - 1) / SCAN_B;  // 49

    // 1) weight prep + bilinear M/r composition (fused, fp8 pre-scales folded)
    prep_kernel<<<(WTOTAL + BTOT + MWORK + 255) / 256, blk, 0, stream>>>(
        Wp, Wq1, Wk1, Wv1, Ws1, Wq2, Wk2, Wv2, Ws2,
        bs1, bq1, bv1, bs2, bq2, bk2, bv2, wt, bb);

    // 2) nf -> bf16, fused with CSR count zero-fill
    const int n4 = NN * FF / 4;
    const int filln = NN + BB * HH + BB;
    cvt_fill_kernel<<<(n4 + filln + 255) / 256, blk, 0, stream>>>(
        (const float4*)nf, (uint2*)nfb, n4, (unsigned*)cnt, filln);

    // 3) CSR build (scan_excl fused into scan_final)
    hist_kernel<<<(EE + 255) / 256, blk, 0, stream>>>(dst, cnt, EE);
    scan_bsum_kernel<<<nb, blk, 0, stream>>>(cnt, bsum, NN);
    scan_final_kernel<<<nb, blk, 0, stream>>>(cnt, bsum, rowptr, cursor, NN);
    bucket_kernel<<<(EE + 255) / 256, blk, 0, stream>>>(src, dst, cursor, srcs, EE);

    // 4) proj: h0b = relu(nf @ Wp + bp)   (mode 0, gx=1, K=64)
    gemm_bf16<<<dim3(1 * gyp), blk, 0, stream>>>(
        nfb, wt, bp, h0b, HH, h0b, 0, NN, FF, 1, 1, gy);

    // 5) F1-mega: [skip(512)->s8 fp8 | per head u|v -> Qb8 fp8]   (mode 1, gx=12, K=128)
    gemm_bf16<<<dim3(12 * gyp), blk, 0, stream>>>(
        h0b, wt + F1OFF, bb, (ushort*)s8, 512, (ushort*)Qb8, 1, NN, HH, 0, 12, gy);

    // 6) fused 4-head gather, 16 lanes/head (fp8 u/v/skip; scale/16 for u pre-scale)
    gather4_kernel<<<(NN + 3) / 4, blk, 0, stream>>>(
        Qb8, h0b, rowptr, srcs, s8, h1b, scale * 0.0625f, NN);

    // 7) F2: [skip(128)->h2sb bf16 | qkv(384)->qkv8 fp8]   (mode 2, gx=4, K=512)
    gemm_bf16<<<dim3(4 * gyp), blk, 0, stream>>>(
        h1b, wt + F2OFF, bb + 1536, h2sb, 128, (ushort*)qkv8, 2, NN, 4 * HH, 0, 4, gy);

    // 8) gather conv2, 4 edge-groups x 16 lanes (fp8 q/k/v; scale/256)
    edge_gather_kernel<<<(NN + 3) / 4, blk, 0, stream>>>(
        qkv8, rowptr, srcs, h2sb, h2, scale * 0.00390625f, NN);

    // 9) pool (relu fused, bf16 input) + finalize
    pool_kernel<<<(NN + 255) / 256, blk, 0, stream>>>(h2, batch, gsum, cntb, NN);
    pool_fin_kernel<<<(BB * HH + 255) / 256, blk, 0, stream>>>(gsum, cntb, gbuf);

    // 10) output heads
    const int total = BB * (1 + 4 + 3 + SS + SS + SS + LCC);
    out_heads_kernel<<<(total + 255) / 256, blk, 0, stream>>>(
        gbuf, crW, crb, hlW, hlb, mtW, mtb, p1W, p1b, p2W, p2b, dtW, dtb, slW, slb, out, total);
}